// Round 3
// baseline (914.519 us; speedup 1.0000x reference)
//
#include <hip/hip_runtime.h>
#include <hip/hip_bf16.h>

typedef __bf16 bf16x8 __attribute__((ext_vector_type(8)));
typedef float  f32x4  __attribute__((ext_vector_type(4)));

#define BSZ 8192

// ---------------- prep: convert w1/w2 to bf16 in GEMM layout [oc][k] ----------------
// k ordering: k = (dy*2+dx)*C + c   (c fastest)
__global__ void k_prep(const float* __restrict__ w1, const float* __restrict__ w2,
                       __bf16* __restrict__ w1b, __bf16* __restrict__ w2b) {
    int t = blockIdx.x * blockDim.x + threadIdx.x;
    if (t < 8192) {           // w1: 64 oc x 128 k
        int oc = t >> 7, k = t & 127, c = k & 31, d = k >> 5;
        w1b[t] = (__bf16)w1[oc * 128 + c * 4 + d];
    }
    if (t < 32768) {          // w2: 128 oc x 256 k
        int oc = t >> 8, k = t & 255, c = k & 63, d = k >> 6;
        w2b[t] = (__bf16)w2[oc * 256 + c * 4 + d];
    }
}

// ---------------- stats for conv0 output (biasless) ----------------
__global__ __launch_bounds__(256) void k_stats0(const float* __restrict__ x,
                                                const float* __restrict__ w0,
                                                float* __restrict__ part0) {
    __shared__ float sw0[288];
    __shared__ float sred[256];
    const int tid = threadIdx.x;
    for (int j = tid; j < 288; j += 256) sw0[j] = w0[j];
    __syncthreads();
    float sum[32], sq[32];
#pragma unroll
    for (int c = 0; c < 32; c++) { sum[c] = 0.f; sq[c] = 0.f; }
    const int total = BSZ * 784;
    for (int p = blockIdx.x * 256 + tid; p < total; p += gridDim.x * 256) {
        int b = p / 784, pix = p - b * 784;
        int y = pix / 28, xx = pix - y * 28;
        const float* xb = x + (long)b * 784;
        float nv[9];
#pragma unroll
        for (int dy = 0; dy < 3; dy++) {
            int yy = y + dy - 1;
#pragma unroll
            for (int dx = 0; dx < 3; dx++) {
                int x2 = xx + dx - 1;
                nv[dy * 3 + dx] = (yy >= 0 && yy < 28 && x2 >= 0 && x2 < 28) ? xb[yy * 28 + x2] : 0.f;
            }
        }
#pragma unroll
        for (int c = 0; c < 32; c++) {
            float a = 0.f;
#pragma unroll
            for (int t = 0; t < 9; t++) a = fmaf(nv[t], sw0[c * 9 + t], a);
            sum[c] += a; sq[c] += a * a;
        }
    }
#pragma unroll
    for (int c = 0; c < 32; c++) {
#pragma unroll
        for (int off = 1; off < 64; off <<= 1) {
            sum[c] += __shfl_xor(sum[c], off);
            sq[c]  += __shfl_xor(sq[c], off);
        }
    }
    const int l = tid & 63, w = tid >> 6;
    if (l == 0) {
#pragma unroll
        for (int c = 0; c < 32; c++) { sred[w * 64 + c] = sum[c]; sred[w * 64 + 32 + c] = sq[c]; }
    }
    __syncthreads();
    if (tid < 64)
        part0[blockIdx.x * 64 + tid] = sred[tid] + sred[64 + tid] + sred[128 + tid] + sred[192 + tid];
}

__global__ void k_fin0(const float* __restrict__ part0, const float* __restrict__ g0,
                       const float* __restrict__ be0, float* __restrict__ abc0) {
    __shared__ float red[256];
    int t = threadIdx.x, s = t & 63, g = t >> 6;
    float acc = 0.f;
    for (int i = g; i < 1024; i += 4) acc += part0[i * 64 + s];
    red[g * 64 + s] = acc;
    __syncthreads();
    if (t < 64) red[t] = red[t] + red[64 + t] + red[128 + t] + red[192 + t];
    __syncthreads();
    if (t < 32) {
        float cnt = (float)(BSZ * 784);
        float mean = red[t] / cnt;
        float var = red[32 + t] / cnt - mean * mean;
        float A = g0[t] * rsqrtf(var + 1e-5f);
        abc0[t] = A;
        abc0[32 + t] = be0[t] - mean * A;
    }
}

// ---------------- fused conv0+BN0+ReLU (LDS) + MFMA conv1 -> h1 (bf16) + stats1 ----------------
// per-image block. A-matrix in LDS: 196(+12 pad) rows x 128 k, row stride 136 elem (272B, odd*16).
__global__ __launch_bounds__(256) void k_conv01(const float* __restrict__ x,
                                                const float* __restrict__ w0,
                                                const float* __restrict__ abc0,
                                                const __bf16* __restrict__ w1b,
                                                __bf16* __restrict__ h1,
                                                float* __restrict__ part1) {
    __shared__ float xs[784];
    __shared__ float sw0[288];
    __shared__ float sbn[64];
    __shared__ __attribute__((aligned(16))) __bf16 sA[208 * 136];
    const int b = blockIdx.x, tid = threadIdx.x;
    for (int j = tid; j < 784; j += 256) xs[j] = x[(long)b * 784 + j];
    for (int j = tid; j < 288; j += 256) sw0[j] = w0[j];
    if (tid < 64) sbn[tid] = abc0[tid];
    // zero pad rows 196..207 (cols 0..127)
    for (int j = tid; j < 12 * 16; j += 256) {
        int r = 196 + (j >> 4), o = (j & 15) * 8;
        bf16x8 z;
#pragma unroll
        for (int q = 0; q < 8; q++) z[q] = (__bf16)0.0f;
        *(bf16x8*)&sA[r * 136 + o] = z;
    }
    __syncthreads();
    // conv0 + BN0 + ReLU -> LDS (im2col layout for conv1)
    for (int p = tid; p < 784; p += 256) {
        int y = p / 28, xx = p - y * 28;
        float nv[9];
#pragma unroll
        for (int dy = 0; dy < 3; dy++) {
            int yy = y + dy - 1;
#pragma unroll
            for (int dx = 0; dx < 3; dx++) {
                int x2 = xx + dx - 1;
                nv[dy * 3 + dx] = (yy >= 0 && yy < 28 && x2 >= 0 && x2 < 28) ? xs[yy * 28 + x2] : 0.f;
            }
        }
        int m = (y >> 1) * 14 + (xx >> 1);
        int kb = ((y & 1) * 2 + (xx & 1)) * 32;
        __bf16* dst = &sA[m * 136 + kb];
#pragma unroll
        for (int g8 = 0; g8 < 4; g8++) {
            bf16x8 pk;
#pragma unroll
            for (int j = 0; j < 8; j++) {
                int c = g8 * 8 + j;
                float a = 0.f;
#pragma unroll
                for (int t = 0; t < 9; t++) a = fmaf(nv[t], sw0[c * 9 + t], a);
                a = fmaxf(a * sbn[c] + sbn[32 + c], 0.f);
                pk[j] = (__bf16)a;
            }
            *(bf16x8*)&dst[g8 * 8] = pk;
        }
    }
    __syncthreads();
    // MFMA conv1: per-wave n-tile (16 oc), 13 m-tiles of 16 rows, K=128
    const int w = tid >> 6, l = tid & 63, q = l >> 4, n = l & 15;
    const int oc = w * 16 + n;
    bf16x8 fbv[4];
#pragma unroll
    for (int kc = 0; kc < 4; kc++)
        fbv[kc] = *(const bf16x8*)&w1b[oc * 128 + kc * 32 + q * 8];
    float ssum = 0.f, ssq = 0.f;
    for (int mt = 0; mt < 13; mt++) {
        bf16x8 fav[4];
#pragma unroll
        for (int kc = 0; kc < 4; kc++)
            fav[kc] = *(const bf16x8*)&sA[(mt * 16 + n) * 136 + kc * 32 + q * 8];
        f32x4 acc = {0.f, 0.f, 0.f, 0.f};
#pragma unroll
        for (int kc = 0; kc < 4; kc++)
            acc = __builtin_amdgcn_mfma_f32_16x16x32_bf16(fav[kc], fbv[kc], acc, 0, 0, 0);
#pragma unroll
        for (int r = 0; r < 4; r++) {
            int m = mt * 16 + q * 4 + r;
            if (m < 196) {
                __bf16 hv = (__bf16)acc[r];
                int oy = m / 14, ox = m - oy * 14;
                int m2 = (oy >> 1) * 7 + (ox >> 1);
                int kk = ((oy & 1) * 2 + (ox & 1)) * 64 + oc;
                h1[(long)b * 12544 + m2 * 256 + kk] = hv;
                float fv = (float)hv;
                ssum += fv; ssq += fv * fv;
            }
        }
    }
    ssum += __shfl_xor(ssum, 16); ssum += __shfl_xor(ssum, 32);
    ssq  += __shfl_xor(ssq, 16);  ssq  += __shfl_xor(ssq, 32);
    if (l < 16) {
        part1[(long)oc * BSZ + b] = ssum;
        part1[(long)(64 + oc) * BSZ + b] = ssq;
    }
}

// ---------------- generic column reducer + BN finalizer ----------------
__global__ void k_red(const float* __restrict__ part, float* __restrict__ red, int rows) {
    __shared__ float sred[256];
    int c = blockIdx.x;
    float a = 0.f;
    for (int i = threadIdx.x; i < rows; i += 256) a += part[(long)c * rows + i];
    sred[threadIdx.x] = a;
    __syncthreads();
    for (int s = 128; s > 0; s >>= 1) {
        if (threadIdx.x < s) sred[threadIdx.x] += sred[threadIdx.x + s];
        __syncthreads();
    }
    if (threadIdx.x == 0) red[c] = sred[0];
}

__global__ void k_fin(const float* __restrict__ red, const float* __restrict__ g,
                      const float* __restrict__ be, float* __restrict__ abc,
                      int C, float cnt) {
    int t = threadIdx.x;
    if (t < C) {
        float mean = red[t] / cnt;
        float var = red[C + t] / cnt - mean * mean;
        float A = g[t] * rsqrtf(var + 1e-5f);
        abc[t] = A;
        abc[C + t] = be[t] - mean * A;
    }
}

// ---------------- conv2 MFMA from h1 (with BN1+ReLU applied on load) -> stats2 only ----------------
// per-image: A = 49(+15 pad) rows x 256 k, LDS stride 264 elem (528B, odd*16).
__global__ __launch_bounds__(256) void k_conv2s(const __bf16* __restrict__ h1,
                                                const __bf16* __restrict__ w2b,
                                                const float* __restrict__ abc1,
                                                float* __restrict__ part2) {
    __shared__ __attribute__((aligned(16))) __bf16 sA[64 * 264];
    __shared__ float sbn1[128];
    const int b = blockIdx.x, tid = threadIdx.x;
    if (tid < 128) sbn1[tid] = abc1[tid];
    __syncthreads();
    const __bf16* src = h1 + (long)b * 12544;
    for (int j = tid; j < 1568; j += 256) {
        int r = j >> 5, o = (j & 31) * 8;
        bf16x8 v = *(const bf16x8*)&src[r * 256 + o];
        bf16x8 wv;
        int cb = o & 63;   // channel = (o+q) & 63; o multiple of 8 so cb+q <= 63
#pragma unroll
        for (int q = 0; q < 8; q++) {
            float f = fmaxf((float)v[q] * sbn1[cb + q] + sbn1[64 + cb + q], 0.f);
            wv[q] = (__bf16)f;
        }
        *(bf16x8*)&sA[r * 264 + o] = wv;
    }
    for (int j = tid; j < 15 * 32; j += 256) {
        int r = 49 + (j >> 5), o = (j & 31) * 8;
        bf16x8 z;
#pragma unroll
        for (int q = 0; q < 8; q++) z[q] = (__bf16)0.0f;
        *(bf16x8*)&sA[r * 264 + o] = z;
    }
    __syncthreads();
    const int w = tid >> 6, l = tid & 63, q = l >> 4, n = l & 15;
    bf16x8 fbv[2][8];
#pragma unroll
    for (int ntl = 0; ntl < 2; ntl++) {
        int oc = (2 * w + ntl) * 16 + n;
#pragma unroll
        for (int kc = 0; kc < 8; kc++)
            fbv[ntl][kc] = *(const bf16x8*)&w2b[oc * 256 + kc * 32 + q * 8];
    }
    float ssum[2] = {0.f, 0.f}, ssq[2] = {0.f, 0.f};
    for (int mt = 0; mt < 4; mt++) {
        bf16x8 fav[8];
#pragma unroll
        for (int kc = 0; kc < 8; kc++)
            fav[kc] = *(const bf16x8*)&sA[(mt * 16 + n) * 264 + kc * 32 + q * 8];
#pragma unroll
        for (int ntl = 0; ntl < 2; ntl++) {
            f32x4 acc = {0.f, 0.f, 0.f, 0.f};
#pragma unroll
            for (int kc = 0; kc < 8; kc++)
                acc = __builtin_amdgcn_mfma_f32_16x16x32_bf16(fav[kc], fbv[ntl][kc], acc, 0, 0, 0);
#pragma unroll
            for (int r = 0; r < 4; r++) { float v = acc[r]; ssum[ntl] += v; ssq[ntl] += v * v; }
        }
    }
#pragma unroll
    for (int ntl = 0; ntl < 2; ntl++) {
        ssum[ntl] += __shfl_xor(ssum[ntl], 16); ssum[ntl] += __shfl_xor(ssum[ntl], 32);
        ssq[ntl]  += __shfl_xor(ssq[ntl], 16);  ssq[ntl]  += __shfl_xor(ssq[ntl], 32);
    }
    if (l < 16) {
#pragma unroll
        for (int ntl = 0; ntl < 2; ntl++) {
            int oc = (2 * w + ntl) * 16 + l;
            part2[(long)oc * BSZ + b] = ssum[ntl];
            part2[(long)(128 + oc) * BSZ + b] = ssq[ntl];
        }
    }
}

// ---------------- conv2 MFMA (BN1+ReLU on load) + BN2 + ReLU + avgpool + FC -> out ----------------
__global__ __launch_bounds__(256) void k_final(const __bf16* __restrict__ h1,
                                               const __bf16* __restrict__ w2b,
                                               const float* __restrict__ abc1,
                                               const float* __restrict__ abc2,
                                               const float* __restrict__ wfc,
                                               const float* __restrict__ bfc,
                                               float* __restrict__ out) {
    __shared__ __attribute__((aligned(16))) __bf16 sA[64 * 264];
    __shared__ float sbn1[128];
    __shared__ float pooled[128];
    __shared__ float fcred[80];
    const int b = blockIdx.x, tid = threadIdx.x;
    if (tid < 128) sbn1[tid] = abc1[tid];
    __syncthreads();
    const __bf16* src = h1 + (long)b * 12544;
    for (int j = tid; j < 1568; j += 256) {
        int r = j >> 5, o = (j & 31) * 8;
        bf16x8 v = *(const bf16x8*)&src[r * 256 + o];
        bf16x8 wv;
        int cb = o & 63;
#pragma unroll
        for (int q = 0; q < 8; q++) {
            float f = fmaxf((float)v[q] * sbn1[cb + q] + sbn1[64 + cb + q], 0.f);
            wv[q] = (__bf16)f;
        }
        *(bf16x8*)&sA[r * 264 + o] = wv;
    }
    for (int j = tid; j < 15 * 32; j += 256) {
        int r = 49 + (j >> 5), o = (j & 31) * 8;
        bf16x8 z;
#pragma unroll
        for (int q = 0; q < 8; q++) z[q] = (__bf16)0.0f;
        *(bf16x8*)&sA[r * 264 + o] = z;
    }
    __syncthreads();
    const int w = tid >> 6, l = tid & 63, q = l >> 4, n = l & 15;
    bf16x8 fbv[2][8];
    float a2[2], c2[2];
#pragma unroll
    for (int ntl = 0; ntl < 2; ntl++) {
        int oc = (2 * w + ntl) * 16 + n;
#pragma unroll
        for (int kc = 0; kc < 8; kc++)
            fbv[ntl][kc] = *(const bf16x8*)&w2b[oc * 256 + kc * 32 + q * 8];
        a2[ntl] = abc2[oc];
        c2[ntl] = abc2[128 + oc];
    }
    float psum[2] = {0.f, 0.f};
    for (int mt = 0; mt < 4; mt++) {
        bf16x8 fav[8];
#pragma unroll
        for (int kc = 0; kc < 8; kc++)
            fav[kc] = *(const bf16x8*)&sA[(mt * 16 + n) * 264 + kc * 32 + q * 8];
#pragma unroll
        for (int ntl = 0; ntl < 2; ntl++) {
            f32x4 acc = {0.f, 0.f, 0.f, 0.f};
#pragma unroll
            for (int kc = 0; kc < 8; kc++)
                acc = __builtin_amdgcn_mfma_f32_16x16x32_bf16(fav[kc], fbv[ntl][kc], acc, 0, 0, 0);
#pragma unroll
            for (int r = 0; r < 4; r++) {
                int m = mt * 16 + q * 4 + r;
                if (m < 49) {
                    float v = fmaxf(acc[r] * a2[ntl] + c2[ntl], 0.f);
                    psum[ntl] += v;
                }
            }
        }
    }
#pragma unroll
    for (int ntl = 0; ntl < 2; ntl++) {
        psum[ntl] += __shfl_xor(psum[ntl], 16);
        psum[ntl] += __shfl_xor(psum[ntl], 32);
    }
    if (l < 16) {
#pragma unroll
        for (int ntl = 0; ntl < 2; ntl++)
            pooled[(2 * w + ntl) * 16 + l] = psum[ntl] * (1.f / 49.f);
    }
    __syncthreads();
    if (tid < 80) {
        int o = tid >> 3, s = tid & 7;
        float a = 0.f;
#pragma unroll
        for (int j = 0; j < 16; j++) a = fmaf(pooled[s * 16 + j], wfc[o * 128 + s * 16 + j], a);
        fcred[tid] = a;
    }
    __syncthreads();
    if (tid < 10) {
        float a = bfc[tid];
#pragma unroll
        for (int s = 0; s < 8; s++) a += fcred[tid * 8 + s];
        out[(long)b * 10 + tid] = a;
    }
}

extern "C" void kernel_launch(void* const* d_in, const int* in_sizes, int n_in,
                              void* d_out, int out_size, void* d_ws, size_t ws_size,
                              hipStream_t stream) {
    const float* x   = (const float*)d_in[0];
    const float* w0  = (const float*)d_in[1];
    const float* g0  = (const float*)d_in[3];
    const float* be0 = (const float*)d_in[4];
    const float* w1  = (const float*)d_in[5];
    const float* g1  = (const float*)d_in[7];
    const float* be1 = (const float*)d_in[8];
    const float* w2  = (const float*)d_in[9];
    const float* g2  = (const float*)d_in[11];
    const float* be2 = (const float*)d_in[12];
    const float* wfc = (const float*)d_in[13];
    const float* bfc = (const float*)d_in[14];
    float* out = (float*)d_out;

    float* ws    = (float*)d_ws;
    float* part0 = ws;                       // 1024*64
    float* abc0  = part0 + 1024 * 64;        // 64
    float* part1 = abc0 + 64;                // 128*8192
    float* red1  = part1 + 128 * BSZ;        // 128
    float* abc1  = red1 + 128;               // 128
    float* part2 = abc1 + 128;               // 256*8192
    float* red2  = part2 + 256 * BSZ;        // 256
    float* abc2  = red2 + 256;               // 256
    __bf16* w1b  = (__bf16*)(abc2 + 256);    // 8192
    __bf16* w2b  = w1b + 8192;               // 32768
    __bf16* h1   = w2b + 32768;              // 8192*12544 bf16 (~205 MB)

    k_prep<<<dim3(128), dim3(256), 0, stream>>>(w1, w2, w1b, w2b);
    k_stats0<<<dim3(1024), dim3(256), 0, stream>>>(x, w0, part0);
    k_fin0<<<dim3(1), dim3(256), 0, stream>>>(part0, g0, be0, abc0);
    k_conv01<<<dim3(BSZ), dim3(256), 0, stream>>>(x, w0, abc0, w1b, h1, part1);
    k_red<<<dim3(128), dim3(256), 0, stream>>>(part1, red1, BSZ);
    k_fin<<<dim3(1), dim3(64), 0, stream>>>(red1, g1, be1, abc1, 64, (float)(BSZ * 196));
    k_conv2s<<<dim3(BSZ), dim3(256), 0, stream>>>(h1, w2b, abc1, part2);
    k_red<<<dim3(256), dim3(256), 0, stream>>>(part2, red2, BSZ);
    k_fin<<<dim3(1), dim3(128), 0, stream>>>(red2, g2, be2, abc2, 128, (float)(BSZ * 49));
    k_final<<<dim3(BSZ), dim3(256), 0, stream>>>(h1, w2b, abc1, abc2, wfc, bfc, out);
}

// Round 4
// 636.411 us; speedup vs baseline: 1.4370x; 1.4370x over previous
//
#include <hip/hip_runtime.h>
#include <hip/hip_bf16.h>

typedef __bf16 bf16x8 __attribute__((ext_vector_type(8)));
typedef float  f32x4  __attribute__((ext_vector_type(4)));

#define BSZ 8192

// ---------------- prep: convert w1/w2 to bf16 in GEMM layout [oc][k] ----------------
// k ordering: k = (dy*2+dx)*C + c   (c fastest)
__global__ void k_prep(const float* __restrict__ w1, const float* __restrict__ w2,
                       __bf16* __restrict__ w1b, __bf16* __restrict__ w2b) {
    int t = blockIdx.x * blockDim.x + threadIdx.x;
    if (t < 8192) {           // w1: 64 oc x 128 k
        int oc = t >> 7, k = t & 127, c = k & 31, d = k >> 5;
        w1b[t] = (__bf16)w1[oc * 128 + c * 4 + d];
    }
    if (t < 32768) {          // w2: 128 oc x 256 k
        int oc = t >> 8, k = t & 255, c = k & 63, d = k >> 6;
        w2b[t] = (__bf16)w2[oc * 256 + c * 4 + d];
    }
}

// ---------------- stats0 via 9x9 second-moment matrix (channel-independent) ----------------
// a[0..44] = upper-triangle M (t outer, u from t), a[45..53] = X[t]
__global__ __launch_bounds__(256) void k_stats0(const float* __restrict__ x,
                                                float* __restrict__ part0) {
    __shared__ float sred[4 * 54];
    const int tid = threadIdx.x;
    float a[54];
#pragma unroll
    for (int i = 0; i < 54; i++) a[i] = 0.f;
    const int total = BSZ * 784;
    for (int p = blockIdx.x * 256 + tid; p < total; p += gridDim.x * 256) {
        int b = p / 784, pix = p - b * 784;
        int y = pix / 28, xx = pix - y * 28;
        const float* xb = x + (long)b * 784;
        float nv[9];
#pragma unroll
        for (int dy = 0; dy < 3; dy++) {
            int yy = y + dy - 1;
#pragma unroll
            for (int dx = 0; dx < 3; dx++) {
                int x2 = xx + dx - 1;
                nv[dy * 3 + dx] = (yy >= 0 && yy < 28 && x2 >= 0 && x2 < 28) ? xb[yy * 28 + x2] : 0.f;
            }
        }
        int idx = 0;
#pragma unroll
        for (int t = 0; t < 9; t++) {
            float vt = nv[t];
            a[45 + t] += vt;
#pragma unroll
            for (int u = t; u < 9; u++) { a[idx] += vt * nv[u]; idx++; }
        }
    }
#pragma unroll
    for (int i = 0; i < 54; i++) {
        float v = a[i];
        v += __shfl_xor(v, 1);  v += __shfl_xor(v, 2);  v += __shfl_xor(v, 4);
        v += __shfl_xor(v, 8);  v += __shfl_xor(v, 16); v += __shfl_xor(v, 32);
        a[i] = v;
    }
    const int l = tid & 63, w = tid >> 6;
    if (l == 0) {
#pragma unroll
        for (int i = 0; i < 54; i++) sred[w * 54 + i] = a[i];
    }
    __syncthreads();
    if (tid < 54)
        part0[blockIdx.x * 64 + tid] = sred[tid] + sred[54 + tid] + sred[108 + tid] + sred[162 + tid];
}

__global__ void k_fin0(const float* __restrict__ part0, const float* __restrict__ w0,
                       const float* __restrict__ g0, const float* __restrict__ be0,
                       float* __restrict__ abc0) {
    __shared__ float red[4 * 54];
    int t = threadIdx.x, c = t & 63, g = t >> 6;
    if (c < 54) {
        float acc = 0.f;
        for (int i = g; i < 1024; i += 4) acc += part0[i * 64 + c];
        red[g * 54 + c] = acc;
    }
    __syncthreads();
    if (t < 54) red[t] = red[t] + red[54 + t] + red[108 + t] + red[162 + t];
    __syncthreads();
    if (t < 32) {
        float wv[9];
#pragma unroll
        for (int tap = 0; tap < 9; tap++) wv[tap] = w0[t * 9 + tap];
        float sum = 0.f, sq = 0.f;
        int idx = 0;
#pragma unroll
        for (int ta = 0; ta < 9; ta++) {
            sum = fmaf(wv[ta], red[45 + ta], sum);
#pragma unroll
            for (int u = ta; u < 9; u++) {
                float coef = (u == ta) ? 1.f : 2.f;
                sq = fmaf(coef * wv[ta] * wv[u], red[idx], sq);
                idx++;
            }
        }
        float cnt = (float)BSZ * 784.f;
        float mean = sum / cnt;
        float var = sq / cnt - mean * mean;
        float A = g0[t] * rsqrtf(var + 1e-5f);
        abc0[t] = A;
        abc0[32 + t] = be0[t] - mean * A;
    }
}

// ---------------- fused conv0+BN0+ReLU (LDS) + MFMA conv1 -> h1 [b][m][oc] + stats1 ----------------
// per-image block. A-matrix in LDS: 196(+12 pad) rows x 128 k, row stride 136 elem (272B, odd*16).
__global__ __launch_bounds__(256) void k_conv01(const float* __restrict__ x,
                                                const float* __restrict__ w0,
                                                const float* __restrict__ abc0,
                                                const __bf16* __restrict__ w1b,
                                                __bf16* __restrict__ h1,
                                                float* __restrict__ part1) {
    __shared__ float xs[30 * 30];   // zero-padded input
    __shared__ float sw0[288];
    __shared__ float sbn[64];
    __shared__ __attribute__((aligned(16))) __bf16 sA[208 * 136];
    const int b = blockIdx.x, tid = threadIdx.x;
    // zero border (116 cells)
    if (tid < 116) {
        int idx;
        if (tid < 30)      idx = tid;
        else if (tid < 60) idx = 29 * 30 + (tid - 30);
        else if (tid < 88) idx = (tid - 60 + 1) * 30;
        else               idx = (tid - 88 + 1) * 30 + 29;
        xs[idx] = 0.f;
    }
    // interior
    for (int j = tid; j < 784; j += 256) {
        int yy = j / 28, xx2 = j - yy * 28;
        xs[(yy + 1) * 30 + xx2 + 1] = x[(long)b * 784 + j];
    }
    for (int j = tid; j < 288; j += 256) sw0[j] = w0[j];
    if (tid < 64) sbn[tid] = abc0[tid];
    // zero pad rows 196..207
    for (int j = tid; j < 12 * 16; j += 256) {
        int r = 196 + (j >> 4), o = (j & 15) * 8;
        bf16x8 z;
#pragma unroll
        for (int q = 0; q < 8; q++) z[q] = (__bf16)0.0f;
        *(bf16x8*)&sA[r * 136 + o] = z;
    }
    __syncthreads();
    // conv0 + BN0 + ReLU -> LDS (im2col layout for conv1), no boundary predication
    for (int p = tid; p < 784; p += 256) {
        int y = p / 28, xx = p - y * 28;
        float nv[9];
#pragma unroll
        for (int dy = 0; dy < 3; dy++)
#pragma unroll
            for (int dx = 0; dx < 3; dx++)
                nv[dy * 3 + dx] = xs[(y + dy) * 30 + xx + dx];
        int m = (y >> 1) * 14 + (xx >> 1);
        int kb = ((y & 1) * 2 + (xx & 1)) * 32;
        __bf16* dst = &sA[m * 136 + kb];
#pragma unroll
        for (int g8 = 0; g8 < 4; g8++) {
            bf16x8 pk;
#pragma unroll
            for (int j = 0; j < 8; j++) {
                int c = g8 * 8 + j;
                float a = 0.f;
#pragma unroll
                for (int t = 0; t < 9; t++) a = fmaf(nv[t], sw0[c * 9 + t], a);
                a = fmaxf(a * sbn[c] + sbn[32 + c], 0.f);
                pk[j] = (__bf16)a;
            }
            *(bf16x8*)&dst[g8 * 8] = pk;
        }
    }
    __syncthreads();
    // MFMA conv1: per-wave n-tile (16 oc), 13 m-tiles of 16 rows, K=128
    const int w = tid >> 6, l = tid & 63, q = l >> 4, n = l & 15;
    const int oc = w * 16 + n;
    bf16x8 fbv[4];
#pragma unroll
    for (int kc = 0; kc < 4; kc++)
        fbv[kc] = *(const bf16x8*)&w1b[oc * 128 + kc * 32 + q * 8];
    float ssum = 0.f, ssq = 0.f;
    __bf16* hb = h1 + (long)b * 12544 + (q * 4) * 64 + oc;
    for (int mt = 0; mt < 13; mt++) {
        bf16x8 fav[4];
#pragma unroll
        for (int kc = 0; kc < 4; kc++)
            fav[kc] = *(const bf16x8*)&sA[(mt * 16 + n) * 136 + kc * 32 + q * 8];
        f32x4 acc = {0.f, 0.f, 0.f, 0.f};
#pragma unroll
        for (int kc = 0; kc < 4; kc++)
            acc = __builtin_amdgcn_mfma_f32_16x16x32_bf16(fav[kc], fbv[kc], acc, 0, 0, 0);
        // store h1[b][m][oc], m = mt*16 + q*4 + r  (valid m<196)
        bool valid = (mt < 12) | (q == 0);
        __bf16* hp = hb + mt * 16 * 64;
#pragma unroll
        for (int r = 0; r < 4; r++) {
            __bf16 hv = (__bf16)acc[r];
            if (valid) hp[r * 64] = hv;
            float fv = (float)hv;               // padded rows give 0 -> no stat effect
            ssum += fv; ssq += fv * fv;
        }
    }
    ssum += __shfl_xor(ssum, 16); ssum += __shfl_xor(ssum, 32);
    ssq  += __shfl_xor(ssq, 16);  ssq  += __shfl_xor(ssq, 32);
    if (l < 16) {
        part1[(long)oc * BSZ + b] = ssum;
        part1[(long)(64 + oc) * BSZ + b] = ssq;
    }
}

// ---------------- generic column reducer + BN finalizer ----------------
__global__ void k_red(const float* __restrict__ part, float* __restrict__ red, int rows) {
    __shared__ float sred[256];
    int c = blockIdx.x;
    float a = 0.f;
    for (int i = threadIdx.x; i < rows; i += 256) a += part[(long)c * rows + i];
    sred[threadIdx.x] = a;
    __syncthreads();
    for (int s = 128; s > 0; s >>= 1) {
        if (threadIdx.x < s) sred[threadIdx.x] += sred[threadIdx.x + s];
        __syncthreads();
    }
    if (threadIdx.x == 0) red[c] = sred[0];
}

__global__ void k_fin(const float* __restrict__ red, const float* __restrict__ g,
                      const float* __restrict__ be, float* __restrict__ abc,
                      int C, float cnt) {
    int t = threadIdx.x;
    if (t < C) {
        float mean = red[t] / cnt;
        float var = red[C + t] / cnt - mean * mean;
        float A = g[t] * rsqrtf(var + 1e-5f);
        abc[t] = A;
        abc[C + t] = be[t] - mean * A;
    }
}

// ---------------- conv2 MFMA (BN1+ReLU on load) -> z2 (bf16, aliased into h1) + stats2 ----------------
// per-image: A = 49(+15 pad) rows x 256 k, LDS stride 264 elem (528B, odd*16).
// z2[b][m2][oc] stored at h1 + b*12544 (first 6272 elems) — safe: all h1[b] reads staged pre-barrier.
__global__ __launch_bounds__(256) void k_conv2s(__bf16* __restrict__ h1,
                                                const __bf16* __restrict__ w2b,
                                                const float* __restrict__ abc1,
                                                float* __restrict__ part2) {
    __shared__ __attribute__((aligned(16))) __bf16 sA[64 * 264];
    __shared__ float sbn1[128];
    const int b = blockIdx.x, tid = threadIdx.x;
    if (tid < 128) sbn1[tid] = abc1[tid];
    __syncthreads();
    const __bf16* src = h1 + (long)b * 12544;
    // stage + im2col remap: sA[r][d*64+c] = BN1ReLU(h1[b][(2*(r/7)+dy)*14 + 2*(r%7)+dx][c])
    for (int j = tid; j < 1568; j += 256) {
        int r = j >> 5, o = (j & 31) * 8;
        int d = o >> 6, c = o & 63;
        int py = r / 7, px = r - py * 7;
        int msrc = (2 * py + (d >> 1)) * 14 + 2 * px + (d & 1);
        bf16x8 v = *(const bf16x8*)&src[msrc * 64 + c];
        bf16x8 wv;
#pragma unroll
        for (int q = 0; q < 8; q++) {
            float f = fmaxf((float)v[q] * sbn1[c + q] + sbn1[64 + c + q], 0.f);
            wv[q] = (__bf16)f;
        }
        *(bf16x8*)&sA[r * 264 + o] = wv;
    }
    for (int j = tid; j < 15 * 32; j += 256) {
        int r = 49 + (j >> 5), o = (j & 31) * 8;
        bf16x8 z;
#pragma unroll
        for (int q = 0; q < 8; q++) z[q] = (__bf16)0.0f;
        *(bf16x8*)&sA[r * 264 + o] = z;
    }
    __syncthreads();
    const int w = tid >> 6, l = tid & 63, q = l >> 4, n = l & 15;
    bf16x8 fbv[2][8];
#pragma unroll
    for (int ntl = 0; ntl < 2; ntl++) {
        int oc = (2 * w + ntl) * 16 + n;
#pragma unroll
        for (int kc = 0; kc < 8; kc++)
            fbv[ntl][kc] = *(const bf16x8*)&w2b[oc * 256 + kc * 32 + q * 8];
    }
    float ssum[2] = {0.f, 0.f}, ssq[2] = {0.f, 0.f};
    __bf16* zb = h1 + (long)b * 12544 + (q * 4) * 128 + (2 * w) * 16 + n;
    for (int mt = 0; mt < 4; mt++) {
        bf16x8 fav[8];
#pragma unroll
        for (int kc = 0; kc < 8; kc++)
            fav[kc] = *(const bf16x8*)&sA[(mt * 16 + n) * 264 + kc * 32 + q * 8];
#pragma unroll
        for (int ntl = 0; ntl < 2; ntl++) {
            f32x4 acc = {0.f, 0.f, 0.f, 0.f};
#pragma unroll
            for (int kc = 0; kc < 8; kc++)
                acc = __builtin_amdgcn_mfma_f32_16x16x32_bf16(fav[kc], fbv[ntl][kc], acc, 0, 0, 0);
            __bf16* zp = zb + mt * 16 * 128 + ntl * 16;
#pragma unroll
            for (int r = 0; r < 4; r++) {
                __bf16 hv = (__bf16)acc[r];
                int m = mt * 16 + q * 4 + r;
                if (m < 49) zp[r * 128] = hv;
                float fv = (float)hv;           // padded rows -> 0
                ssum[ntl] += fv; ssq[ntl] += fv * fv;
            }
        }
    }
#pragma unroll
    for (int ntl = 0; ntl < 2; ntl++) {
        ssum[ntl] += __shfl_xor(ssum[ntl], 16); ssum[ntl] += __shfl_xor(ssum[ntl], 32);
        ssq[ntl]  += __shfl_xor(ssq[ntl], 16);  ssq[ntl]  += __shfl_xor(ssq[ntl], 32);
    }
    if (l < 16) {
#pragma unroll
        for (int ntl = 0; ntl < 2; ntl++) {
            int oc = (2 * w + ntl) * 16 + l;
            part2[(long)oc * BSZ + b] = ssum[ntl];
            part2[(long)(128 + oc) * BSZ + b] = ssq[ntl];
        }
    }
}

// ---------------- light epilogue: BN2 + ReLU + avgpool + FC from z2 ----------------
__global__ __launch_bounds__(256) void k_final(const __bf16* __restrict__ z2,
                                               const float* __restrict__ abc2,
                                               const float* __restrict__ wfc,
                                               const float* __restrict__ bfc,
                                               float* __restrict__ out) {
    __shared__ float sbn2[256];
    __shared__ float pp[16 * 128];
    __shared__ float pooled[128];
    __shared__ float fcred[80];
    const int b = blockIdx.x, tid = threadIdx.x;
    sbn2[tid] = abc2[tid];
    __syncthreads();
    const int g = tid & 15, c0 = g * 8, rg = tid >> 4;
    const __bf16* src = z2 + (long)b * 12544;
    float acc[8];
#pragma unroll
    for (int q = 0; q < 8; q++) acc[q] = 0.f;
    for (int rr = rg; rr < 49; rr += 16) {
        bf16x8 v = *(const bf16x8*)&src[rr * 128 + c0];
#pragma unroll
        for (int q = 0; q < 8; q++) {
            float f = fmaxf((float)v[q] * sbn2[c0 + q] + sbn2[128 + c0 + q], 0.f);
            acc[q] += f;
        }
    }
    *(f32x4*)&pp[rg * 128 + c0]     = *(f32x4*)&acc[0];
    *(f32x4*)&pp[rg * 128 + c0 + 4] = *(f32x4*)&acc[4];
    __syncthreads();
    if (tid < 128) {
        float s = 0.f;
#pragma unroll
        for (int r = 0; r < 16; r++) s += pp[r * 128 + tid];
        pooled[tid] = s * (1.f / 49.f);
    }
    __syncthreads();
    if (tid < 80) {
        int o = tid >> 3, s = tid & 7;
        float a = 0.f;
#pragma unroll
        for (int j = 0; j < 16; j++) a = fmaf(pooled[s * 16 + j], wfc[o * 128 + s * 16 + j], a);
        fcred[tid] = a;
    }
    __syncthreads();
    if (tid < 10) {
        float a = bfc[tid];
#pragma unroll
        for (int s = 0; s < 8; s++) a += fcred[tid * 8 + s];
        out[(long)b * 10 + tid] = a;
    }
}

extern "C" void kernel_launch(void* const* d_in, const int* in_sizes, int n_in,
                              void* d_out, int out_size, void* d_ws, size_t ws_size,
                              hipStream_t stream) {
    const float* x   = (const float*)d_in[0];
    const float* w0  = (const float*)d_in[1];
    const float* g0  = (const float*)d_in[3];
    const float* be0 = (const float*)d_in[4];
    const float* w1  = (const float*)d_in[5];
    const float* g1  = (const float*)d_in[7];
    const float* be1 = (const float*)d_in[8];
    const float* w2  = (const float*)d_in[9];
    const float* g2  = (const float*)d_in[11];
    const float* be2 = (const float*)d_in[12];
    const float* wfc = (const float*)d_in[13];
    const float* bfc = (const float*)d_in[14];
    float* out = (float*)d_out;

    float* ws    = (float*)d_ws;
    float* part0 = ws;                       // 1024*64
    float* abc0  = part0 + 1024 * 64;        // 64
    float* part1 = abc0 + 64;                // 128*8192
    float* red1  = part1 + 128 * BSZ;        // 128
    float* abc1  = red1 + 128;               // 128
    float* part2 = abc1 + 128;               // 256*8192
    float* red2  = part2 + 256 * BSZ;        // 256
    float* abc2  = red2 + 256;               // 256
    __bf16* w1b  = (__bf16*)(abc2 + 256);    // 8192
    __bf16* w2b  = w1b + 8192;               // 32768
    __bf16* h1   = w2b + 32768;              // 8192*12544 bf16 (~205 MB); z2 aliased per-image

    k_prep<<<dim3(128), dim3(256), 0, stream>>>(w1, w2, w1b, w2b);
    k_stats0<<<dim3(1024), dim3(256), 0, stream>>>(x, part0);
    k_fin0<<<dim3(1), dim3(256), 0, stream>>>(part0, w0, g0, be0, abc0);
    k_conv01<<<dim3(BSZ), dim3(256), 0, stream>>>(x, w0, abc0, w1b, h1, part1);
    k_red<<<dim3(128), dim3(256), 0, stream>>>(part1, red1, BSZ);
    k_fin<<<dim3(1), dim3(64), 0, stream>>>(red1, g1, be1, abc1, 64, (float)(BSZ * 196));
    k_conv2s<<<dim3(BSZ), dim3(256), 0, stream>>>(h1, w2b, abc1, part2);
    k_red<<<dim3(256), dim3(256), 0, stream>>>(part2, red2, BSZ);
    k_fin<<<dim3(1), dim3(128), 0, stream>>>(red2, g2, be2, abc2, 128, (float)(BSZ * 49));
    k_final<<<dim3(BSZ), dim3(256), 0, stream>>>(h1, abc2, wfc, bfc, out);
}

// Round 5
// 464.442 us; speedup vs baseline: 1.9691x; 1.3703x over previous
//
#include <hip/hip_runtime.h>
#include <hip/hip_bf16.h>

typedef __bf16 bf16x8 __attribute__((ext_vector_type(8)));
typedef float  f32x4  __attribute__((ext_vector_type(4)));

#define BSZ 8192

// ---------------- prep: convert w1/w2 to bf16 in GEMM layout [oc][k] ----------------
// k ordering: k = (dy*2+dx)*C + c   (c fastest)
__global__ void k_prep(const float* __restrict__ w1, const float* __restrict__ w2,
                       __bf16* __restrict__ w1b, __bf16* __restrict__ w2b) {
    int t = blockIdx.x * blockDim.x + threadIdx.x;
    if (t < 8192) {           // w1: 64 oc x 128 k
        int oc = t >> 7, k = t & 127, c = k & 31, d = k >> 5;
        w1b[t] = (__bf16)w1[oc * 128 + c * 4 + d];
    }
    if (t < 32768) {          // w2: 128 oc x 256 k
        int oc = t >> 8, k = t & 255, c = k & 63, d = k >> 6;
        w2b[t] = (__bf16)w2[oc * 256 + c * 4 + d];
    }
}

// ---------------- stats0 via 9x9 second-moment matrix (channel-independent) ----------------
__global__ __launch_bounds__(256) void k_stats0(const float* __restrict__ x,
                                                float* __restrict__ part0) {
    __shared__ float sred[4 * 54];
    const int tid = threadIdx.x;
    float a[54];
#pragma unroll
    for (int i = 0; i < 54; i++) a[i] = 0.f;
    const int total = BSZ * 784;
    for (int p = blockIdx.x * 256 + tid; p < total; p += gridDim.x * 256) {
        int b = p / 784, pix = p - b * 784;
        int y = pix / 28, xx = pix - y * 28;
        const float* xb = x + (long)b * 784;
        float nv[9];
#pragma unroll
        for (int dy = 0; dy < 3; dy++) {
            int yy = y + dy - 1;
#pragma unroll
            for (int dx = 0; dx < 3; dx++) {
                int x2 = xx + dx - 1;
                nv[dy * 3 + dx] = (yy >= 0 && yy < 28 && x2 >= 0 && x2 < 28) ? xb[yy * 28 + x2] : 0.f;
            }
        }
        int idx = 0;
#pragma unroll
        for (int t = 0; t < 9; t++) {
            float vt = nv[t];
            a[45 + t] += vt;
#pragma unroll
            for (int u = t; u < 9; u++) { a[idx] += vt * nv[u]; idx++; }
        }
    }
#pragma unroll
    for (int i = 0; i < 54; i++) {
        float v = a[i];
        v += __shfl_xor(v, 1);  v += __shfl_xor(v, 2);  v += __shfl_xor(v, 4);
        v += __shfl_xor(v, 8);  v += __shfl_xor(v, 16); v += __shfl_xor(v, 32);
        a[i] = v;
    }
    const int l = tid & 63, w = tid >> 6;
    if (l == 0) {
#pragma unroll
        for (int i = 0; i < 54; i++) sred[w * 54 + i] = a[i];
    }
    __syncthreads();
    if (tid < 54)
        part0[blockIdx.x * 64 + tid] = sred[tid] + sred[54 + tid] + sred[108 + tid] + sred[162 + tid];
}

__global__ void k_fin0(const float* __restrict__ part0, const float* __restrict__ w0,
                       const float* __restrict__ g0, const float* __restrict__ be0,
                       float* __restrict__ abc0) {
    __shared__ float red[4 * 54];
    int t = threadIdx.x, c = t & 63, g = t >> 6;
    if (c < 54) {
        float acc = 0.f;
        for (int i = g; i < 1024; i += 4) acc += part0[i * 64 + c];
        red[g * 54 + c] = acc;
    }
    __syncthreads();
    if (t < 54) red[t] = red[t] + red[54 + t] + red[108 + t] + red[162 + t];
    __syncthreads();
    if (t < 32) {
        float wv[9];
#pragma unroll
        for (int tap = 0; tap < 9; tap++) wv[tap] = w0[t * 9 + tap];
        float sum = 0.f, sq = 0.f;
        int idx = 0;
#pragma unroll
        for (int ta = 0; ta < 9; ta++) {
            sum = fmaf(wv[ta], red[45 + ta], sum);
#pragma unroll
            for (int u = ta; u < 9; u++) {
                float coef = (u == ta) ? 1.f : 2.f;
                sq = fmaf(coef * wv[ta] * wv[u], red[idx], sq);
                idx++;
            }
        }
        float cnt = (float)BSZ * 784.f;
        float mean = sum / cnt;
        float var = sq / cnt - mean * mean;
        float A = g0[t] * rsqrtf(var + 1e-5f);
        abc0[t] = A;
        abc0[32 + t] = be0[t] - mean * A;
    }
}

// ---------------- fused conv0+BN0+ReLU + MFMA conv1, streamed 16-row tiles ----------------
// double-buffered tile: 16 rows x 128 k, row stride 136 elem (272B). One barrier/tile.
// producer: tid -> (row i = tid&15, sub-pixel d = (tid>>4)&3, channel-group g8 = tid>>6).
// g8 == wave id -> weight/BN LDS reads are wave-uniform broadcasts.
__global__ __launch_bounds__(256) void k_conv01(const float* __restrict__ x,
                                                const float* __restrict__ w0,
                                                const float* __restrict__ abc0,
                                                const __bf16* __restrict__ w1b,
                                                __bf16* __restrict__ h1,
                                                float* __restrict__ part1) {
    __shared__ float xs[30 * 30];     // zero-padded input
    __shared__ float swT[9 * 32];     // w0 transposed [tap][c]
    __shared__ float sbn[64];
    __shared__ __attribute__((aligned(16))) __bf16 sAt[2][16 * 136];
    const int b = blockIdx.x, tid = threadIdx.x;
    // zero border (116 cells)
    if (tid < 116) {
        int idx;
        if (tid < 30)      idx = tid;
        else if (tid < 60) idx = 29 * 30 + (tid - 30);
        else if (tid < 88) idx = (tid - 60 + 1) * 30;
        else               idx = (tid - 88 + 1) * 30 + 29;
        xs[idx] = 0.f;
    }
    for (int j = tid; j < 784; j += 256) {
        int yy = j / 28, xx2 = j - yy * 28;
        xs[(yy + 1) * 30 + xx2 + 1] = x[(long)b * 784 + j];
    }
    for (int j = tid; j < 288; j += 256) {
        int c = j >> 3 == 36 ? 0 : 0;  // placeholder no-op
        int cc = j / 9, tap = j - cc * 9;
        swT[tap * 32 + cc] = w0[j];
    }
    if (tid < 64) sbn[tid] = abc0[tid];

    // producer indices
    const int pi = tid & 15, pd = (tid >> 4) & 3, pg = tid >> 6;
    const int pc0 = pg * 8;
    // consumer indices
    const int w = tid >> 6, l = tid & 63, q = l >> 4, n = l & 15;
    const int oc = w * 16 + n;
    bf16x8 fbv[4];
#pragma unroll
    for (int kc = 0; kc < 4; kc++)
        fbv[kc] = *(const bf16x8*)&w1b[oc * 128 + kc * 32 + q * 8];
    float ssum = 0.f, ssq = 0.f;
    __bf16* hb = h1 + (long)b * 12544 + (q * 4) * 64 + oc;
    __syncthreads();

    for (int mt = 0; mt < 13; mt++) {
        // ---- produce tile mt into sAt[mt&1] ----
        __bf16* dst = &sAt[mt & 1][pi * 136 + pd * 32 + pc0];
        int m = mt * 16 + pi;
        bf16x8 pk;
        if (m < 196) {
            int my = m / 14, mx = m - my * 14;
            int y0 = my * 2 + (pd >> 1), x0 = mx * 2 + (pd & 1);
            float nv[9];
#pragma unroll
            for (int dy = 0; dy < 3; dy++)
#pragma unroll
                for (int dx = 0; dx < 3; dx++)
                    nv[dy * 3 + dx] = xs[(y0 + dy) * 30 + x0 + dx];
            float a[8];
#pragma unroll
            for (int j = 0; j < 8; j++) a[j] = 0.f;
#pragma unroll
            for (int t = 0; t < 9; t++) {
                f32x4 w4a = *(const f32x4*)&swT[t * 32 + pc0];
                f32x4 w4b = *(const f32x4*)&swT[t * 32 + pc0 + 4];
#pragma unroll
                for (int j = 0; j < 4; j++) {
                    a[j]     = fmaf(nv[t], w4a[j], a[j]);
                    a[j + 4] = fmaf(nv[t], w4b[j], a[j + 4]);
                }
            }
#pragma unroll
            for (int j = 0; j < 8; j++) {
                float v = fmaxf(a[j] * sbn[pc0 + j] + sbn[32 + pc0 + j], 0.f);
                pk[j] = (__bf16)v;
            }
        } else {
#pragma unroll
            for (int j = 0; j < 8; j++) pk[j] = (__bf16)0.0f;
        }
        *(bf16x8*)dst = pk;
        __syncthreads();
        // ---- consume tile mt ----
        const __bf16* sa = &sAt[mt & 1][n * 136 + q * 8];
        f32x4 acc = {0.f, 0.f, 0.f, 0.f};
#pragma unroll
        for (int kc = 0; kc < 4; kc++) {
            bf16x8 fav = *(const bf16x8*)&sa[kc * 32];
            acc = __builtin_amdgcn_mfma_f32_16x16x32_bf16(fav, fbv[kc], acc, 0, 0, 0);
        }
        bool valid = (mt < 12) | (q == 0);
        __bf16* hp = hb + mt * 16 * 64;
#pragma unroll
        for (int r = 0; r < 4; r++) {
            __bf16 hv = (__bf16)acc[r];
            if (valid) hp[r * 64] = hv;
            float fv = (float)hv;               // padded rows give 0 -> no stat effect
            ssum += fv; ssq += fv * fv;
        }
    }
    ssum += __shfl_xor(ssum, 16); ssum += __shfl_xor(ssum, 32);
    ssq  += __shfl_xor(ssq, 16);  ssq  += __shfl_xor(ssq, 32);
    if (l < 16) {
        part1[(long)oc * BSZ + b] = ssum;
        part1[(long)(64 + oc) * BSZ + b] = ssq;
    }
}

// ---------------- generic column reducer + BN finalizer ----------------
__global__ void k_red(const float* __restrict__ part, float* __restrict__ red, int rows) {
    __shared__ float sred[256];
    int c = blockIdx.x;
    float a = 0.f;
    for (int i = threadIdx.x; i < rows; i += 256) a += part[(long)c * rows + i];
    sred[threadIdx.x] = a;
    __syncthreads();
    for (int s = 128; s > 0; s >>= 1) {
        if (threadIdx.x < s) sred[threadIdx.x] += sred[threadIdx.x + s];
        __syncthreads();
    }
    if (threadIdx.x == 0) red[c] = sred[0];
}

__global__ void k_fin(const float* __restrict__ red, const float* __restrict__ g,
                      const float* __restrict__ be, float* __restrict__ abc,
                      int C, float cnt) {
    int t = threadIdx.x;
    if (t < C) {
        float mean = red[t] / cnt;
        float var = red[C + t] / cnt - mean * mean;
        float A = g[t] * rsqrtf(var + 1e-5f);
        abc[t] = A;
        abc[C + t] = be[t] - mean * A;
    }
}

// ---------------- conv2 MFMA (BN1+ReLU on load) -> z2 (bf16, aliased into h1) + stats2 ----------------
__global__ __launch_bounds__(256) void k_conv2s(__bf16* __restrict__ h1,
                                                const __bf16* __restrict__ w2b,
                                                const float* __restrict__ abc1,
                                                float* __restrict__ part2) {
    __shared__ __attribute__((aligned(16))) __bf16 sA[64 * 264];
    __shared__ float sbn1[128];
    const int b = blockIdx.x, tid = threadIdx.x;
    if (tid < 128) sbn1[tid] = abc1[tid];
    __syncthreads();
    const __bf16* src = h1 + (long)b * 12544;
    for (int j = tid; j < 1568; j += 256) {
        int r = j >> 5, o = (j & 31) * 8;
        int d = o >> 6, c = o & 63;
        int py = r / 7, px = r - py * 7;
        int msrc = (2 * py + (d >> 1)) * 14 + 2 * px + (d & 1);
        bf16x8 v = *(const bf16x8*)&src[msrc * 64 + c];
        bf16x8 wv;
#pragma unroll
        for (int q = 0; q < 8; q++) {
            float f = fmaxf((float)v[q] * sbn1[c + q] + sbn1[64 + c + q], 0.f);
            wv[q] = (__bf16)f;
        }
        *(bf16x8*)&sA[r * 264 + o] = wv;
    }
    for (int j = tid; j < 15 * 32; j += 256) {
        int r = 49 + (j >> 5), o = (j & 31) * 8;
        bf16x8 z;
#pragma unroll
        for (int q = 0; q < 8; q++) z[q] = (__bf16)0.0f;
        *(bf16x8*)&sA[r * 264 + o] = z;
    }
    __syncthreads();
    const int w = tid >> 6, l = tid & 63, q = l >> 4, n = l & 15;
    bf16x8 fbv[2][8];
#pragma unroll
    for (int ntl = 0; ntl < 2; ntl++) {
        int oc = (2 * w + ntl) * 16 + n;
#pragma unroll
        for (int kc = 0; kc < 8; kc++)
            fbv[ntl][kc] = *(const bf16x8*)&w2b[oc * 256 + kc * 32 + q * 8];
    }
    float ssum[2] = {0.f, 0.f}, ssq[2] = {0.f, 0.f};
    __bf16* zb = h1 + (long)b * 12544 + (q * 4) * 128 + (2 * w) * 16 + n;
    for (int mt = 0; mt < 4; mt++) {
        bf16x8 fav[8];
#pragma unroll
        for (int kc = 0; kc < 8; kc++)
            fav[kc] = *(const bf16x8*)&sA[(mt * 16 + n) * 264 + kc * 32 + q * 8];
#pragma unroll
        for (int ntl = 0; ntl < 2; ntl++) {
            f32x4 acc = {0.f, 0.f, 0.f, 0.f};
#pragma unroll
            for (int kc = 0; kc < 8; kc++)
                acc = __builtin_amdgcn_mfma_f32_16x16x32_bf16(fav[kc], fbv[ntl][kc], acc, 0, 0, 0);
            __bf16* zp = zb + mt * 16 * 128 + ntl * 16;
#pragma unroll
            for (int r = 0; r < 4; r++) {
                __bf16 hv = (__bf16)acc[r];
                int m = mt * 16 + q * 4 + r;
                if (m < 49) zp[r * 128] = hv;
                float fv = (float)hv;           // padded rows -> 0
                ssum[ntl] += fv; ssq[ntl] += fv * fv;
            }
        }
    }
#pragma unroll
    for (int ntl = 0; ntl < 2; ntl++) {
        ssum[ntl] += __shfl_xor(ssum[ntl], 16); ssum[ntl] += __shfl_xor(ssum[ntl], 32);
        ssq[ntl]  += __shfl_xor(ssq[ntl], 16);  ssq[ntl]  += __shfl_xor(ssq[ntl], 32);
    }
    if (l < 16) {
#pragma unroll
        for (int ntl = 0; ntl < 2; ntl++) {
            int oc = (2 * w + ntl) * 16 + l;
            part2[(long)oc * BSZ + b] = ssum[ntl];
            part2[(long)(128 + oc) * BSZ + b] = ssq[ntl];
        }
    }
}

// ---------------- light epilogue: BN2 + ReLU + avgpool + FC from z2 ----------------
__global__ __launch_bounds__(256) void k_final(const __bf16* __restrict__ z2,
                                               const float* __restrict__ abc2,
                                               const float* __restrict__ wfc,
                                               const float* __restrict__ bfc,
                                               float* __restrict__ out) {
    __shared__ float sbn2[256];
    __shared__ float pp[16 * 128];
    __shared__ float pooled[128];
    __shared__ float fcred[80];
    const int b = blockIdx.x, tid = threadIdx.x;
    sbn2[tid] = abc2[tid];
    __syncthreads();
    const int g = tid & 15, c0 = g * 8, rg = tid >> 4;
    const __bf16* src = z2 + (long)b * 12544;
    float acc[8];
#pragma unroll
    for (int q = 0; q < 8; q++) acc[q] = 0.f;
    for (int rr = rg; rr < 49; rr += 16) {
        bf16x8 v = *(const bf16x8*)&src[rr * 128 + c0];
#pragma unroll
        for (int q = 0; q < 8; q++) {
            float f = fmaxf((float)v[q] * sbn2[c0 + q] + sbn2[128 + c0 + q], 0.f);
            acc[q] += f;
        }
    }
    *(f32x4*)&pp[rg * 128 + c0]     = *(f32x4*)&acc[0];
    *(f32x4*)&pp[rg * 128 + c0 + 4] = *(f32x4*)&acc[4];
    __syncthreads();
    if (tid < 128) {
        float s = 0.f;
#pragma unroll
        for (int r = 0; r < 16; r++) s += pp[r * 128 + tid];
        pooled[tid] = s * (1.f / 49.f);
    }
    __syncthreads();
    if (tid < 80) {
        int o = tid >> 3, s = tid & 7;
        float a = 0.f;
#pragma unroll
        for (int j = 0; j < 16; j++) a = fmaf(pooled[s * 16 + j], wfc[o * 128 + s * 16 + j], a);
        fcred[tid] = a;
    }
    __syncthreads();
    if (tid < 10) {
        float a = bfc[tid];
#pragma unroll
        for (int s = 0; s < 8; s++) a += fcred[tid * 8 + s];
        out[(long)b * 10 + tid] = a;
    }
}

extern "C" void kernel_launch(void* const* d_in, const int* in_sizes, int n_in,
                              void* d_out, int out_size, void* d_ws, size_t ws_size,
                              hipStream_t stream) {
    const float* x   = (const float*)d_in[0];
    const float* w0  = (const float*)d_in[1];
    const float* g0  = (const float*)d_in[3];
    const float* be0 = (const float*)d_in[4];
    const float* w1  = (const float*)d_in[5];
    const float* g1  = (const float*)d_in[7];
    const float* be1 = (const float*)d_in[8];
    const float* w2  = (const float*)d_in[9];
    const float* g2  = (const float*)d_in[11];
    const float* be2 = (const float*)d_in[12];
    const float* wfc = (const float*)d_in[13];
    const float* bfc = (const float*)d_in[14];
    float* out = (float*)d_out;

    float* ws    = (float*)d_ws;
    float* part0 = ws;                       // 1024*64
    float* abc0  = part0 + 1024 * 64;        // 64
    float* part1 = abc0 + 64;                // 128*8192
    float* red1  = part1 + 128 * BSZ;        // 128
    float* abc1  = red1 + 128;               // 128
    float* part2 = abc1 + 128;               // 256*8192
    float* red2  = part2 + 256 * BSZ;        // 256
    float* abc2  = red2 + 256;               // 256
    __bf16* w1b  = (__bf16*)(abc2 + 256);    // 8192
    __bf16* w2b  = w1b + 8192;               // 32768
    __bf16* h1   = w2b + 32768;              // 8192*12544 bf16 (~205 MB); z2 aliased per-image

    k_prep<<<dim3(128), dim3(256), 0, stream>>>(w1, w2, w1b, w2b);
    k_stats0<<<dim3(1024), dim3(256), 0, stream>>>(x, part0);
    k_fin0<<<dim3(1), dim3(256), 0, stream>>>(part0, w0, g0, be0, abc0);
    k_conv01<<<dim3(BSZ), dim3(256), 0, stream>>>(x, w0, abc0, w1b, h1, part1);
    k_red<<<dim3(128), dim3(256), 0, stream>>>(part1, red1, BSZ);
    k_fin<<<dim3(1), dim3(64), 0, stream>>>(red1, g1, be1, abc1, 64, (float)(BSZ * 196));
    k_conv2s<<<dim3(BSZ), dim3(256), 0, stream>>>(h1, w2b, abc1, part2);
    k_red<<<dim3(256), dim3(256), 0, stream>>>(part2, red2, BSZ);
    k_fin<<<dim3(1), dim3(128), 0, stream>>>(red2, g2, be2, abc2, 128, (float)(BSZ * 49));
    k_final<<<dim3(BSZ), dim3(256), 0, stream>>>(h1, abc2, wfc, bfc, out);
}